// Round 8
// baseline (361.678 us; speedup 1.0000x reference)
//
#include <hip/hip_runtime.h>
#include <math.h>

#define Sn 4
#define Bn 8
#define Ln 512
#define Dn 128
#define Hn 128
#define NOPn 64
#define Wn 2048

// ESTABLISHED: inputs fp32 insertion order; output fp32; bf16-space compare
// (thr 3.6e-2); ws = 512MB; harness tax ~220-260us/iter (restore+poison+gaps,
// ~10us per dispatch; 512MB poison fill alone is 78us @86% HBM peak).
// R20 362 (4k). R21 354 (3k). R22-R26: in-kernel completion schemes all lose
// to the kernel boundary. R27 350.6: bf16 upWbf + fused ww&wem + k-split.
// R28 345.0: wide loads (uint4 GEMV, ushort4 gathers). Key datum: grid
// 8192->4097 left mega at ~104us => duration ~ active blocks' LIFETIME
// (~25us each at ~3 blocks/CU) not work (~5us) -> serialized phase latency.
// R29 (this): TWO slots per block (grid 2048), phases fused pairwise so both
// slots' loads are in flight together (2x MLP per phase), upWbf loaded once
// per block for both slots, all 4 waves busy in oph/p4, 3 barriers/slot.

__device__ __forceinline__ float bf2f(unsigned short u) {
    return __uint_as_float(((unsigned int)u) << 16);
}
__device__ __forceinline__ float bflo(unsigned int u) {
    return __uint_as_float(u << 16);
}
__device__ __forceinline__ float bfhi(unsigned int u) {
    return __uint_as_float(u & 0xFFFF0000u);
}
__device__ __forceinline__ unsigned short f2bf(float f) {
    unsigned int u = __float_as_uint(f);
    return (unsigned short)((u + 0x7FFFu + ((u >> 16) & 1u)) >> 16);  // RNE
}

// ---------------------------------------------------------------------------
// prep_k: blockIdx branches.
//   0..255   : dual GEMM tile (wkh/wsh from word_outputs)
//   256..263 : op-embedding GEMM tile (oph)
//   264..271 : compact pooled indices for b = bid-264 (cap 512)
//   272      : zero gwacc
//   273..274 : convert upW (384x128 fp32) -> upWbf (bf16)
// ---------------------------------------------------------------------------
__global__ __launch_bounds__(256) void prep_k(const float* __restrict__ A,
                                              const float* __restrict__ W1,
                                              const float* __restrict__ W2,
                                              const float* __restrict__ b1,
                                              const float* __restrict__ b2,
                                              unsigned short* __restrict__ C1,
                                              unsigned short* __restrict__ C2,
                                              const float* __restrict__ ope,
                                              const float* __restrict__ owW,
                                              const float* __restrict__ owb,
                                              unsigned short* __restrict__ oph,
                                              const float* __restrict__ goal,
                                              const float* __restrict__ wes,
                                              int* __restrict__ widx,
                                              int* __restrict__ wcnt,
                                              float* __restrict__ gwacc,
                                              const float* __restrict__ upW,
                                              unsigned short* __restrict__ upWbf) {
    __shared__ __align__(16) float lA[32][68];
    __shared__ __align__(16) float lW1[32][132];
    __shared__ __align__(16) float lW2[32][132];
    __shared__ int cnt;
    const int bid = blockIdx.x, tid = threadIdx.x;

    if (bid < 256) {  // ---- dual GEMM ----
        const int m0 = bid * 64;
        float acc1[4][8] = {}, acc2[4][8] = {};
        const int r0 = (tid & 15) * 4;
        const int h0 = (tid >> 4) * 8;
        for (int k0 = 0; k0 < 128; k0 += 32) {
            __syncthreads();
            {
                const int r = tid >> 2, kk = (tid & 3) * 8;
                const float* src = A + (size_t)(m0 + r) * 128 + (k0 + kk);
                float4 v0 = reinterpret_cast<const float4*>(src)[0];
                float4 v1 = reinterpret_cast<const float4*>(src)[1];
                lA[kk + 0][r] = v0.x; lA[kk + 1][r] = v0.y;
                lA[kk + 2][r] = v0.z; lA[kk + 3][r] = v0.w;
                lA[kk + 4][r] = v1.x; lA[kk + 5][r] = v1.y;
                lA[kk + 6][r] = v1.z; lA[kk + 7][r] = v1.w;
            }
            {
                const int kk = tid >> 3, hh = (tid & 7) * 16;
                const float* s1 = W1 + (size_t)(k0 + kk) * 128 + hh;
                const float* s2 = W2 + (size_t)(k0 + kk) * 128 + hh;
#pragma unroll
                for (int q = 0; q < 4; ++q) {
                    float4 v1 = reinterpret_cast<const float4*>(s1)[q];
                    float4 v2 = reinterpret_cast<const float4*>(s2)[q];
                    lW1[kk][hh + 4 * q + 0] = v1.x; lW1[kk][hh + 4 * q + 1] = v1.y;
                    lW1[kk][hh + 4 * q + 2] = v1.z; lW1[kk][hh + 4 * q + 3] = v1.w;
                    lW2[kk][hh + 4 * q + 0] = v2.x; lW2[kk][hh + 4 * q + 1] = v2.y;
                    lW2[kk][hh + 4 * q + 2] = v2.z; lW2[kk][hh + 4 * q + 3] = v2.w;
                }
            }
            __syncthreads();
#pragma unroll
            for (int k = 0; k < 32; ++k) {
                float4 a   = *reinterpret_cast<const float4*>(&lA[k][r0]);
                float4 w10 = *reinterpret_cast<const float4*>(&lW1[k][h0]);
                float4 w11 = *reinterpret_cast<const float4*>(&lW1[k][h0 + 4]);
                float4 w20 = *reinterpret_cast<const float4*>(&lW2[k][h0]);
                float4 w21 = *reinterpret_cast<const float4*>(&lW2[k][h0 + 4]);
                float av[4] = {a.x, a.y, a.z, a.w};
                float wv1[8] = {w10.x, w10.y, w10.z, w10.w, w11.x, w11.y, w11.z, w11.w};
                float wv2[8] = {w20.x, w20.y, w20.z, w20.w, w21.x, w21.y, w21.z, w21.w};
#pragma unroll
                for (int i = 0; i < 4; ++i)
#pragma unroll
                    for (int j = 0; j < 8; ++j) {
                        acc1[i][j] = fmaf(av[i], wv1[j], acc1[i][j]);
                        acc2[i][j] = fmaf(av[i], wv2[j], acc2[i][j]);
                    }
            }
        }
#pragma unroll
        for (int i = 0; i < 4; ++i) {
            alignas(16) unsigned short u1[8], u2[8];
#pragma unroll
            for (int j = 0; j < 8; ++j) {
                u1[j] = f2bf(acc1[i][j] + b1[h0 + j]);
                u2[j] = f2bf(acc2[i][j] + b2[h0 + j]);
            }
            const size_t off = (size_t)(m0 + r0 + i) * 128 + h0;
            *reinterpret_cast<uint4*>(C1 + off) = *reinterpret_cast<const uint4*>(u1);
            *reinterpret_cast<uint4*>(C2 + off) = *reinterpret_cast<const uint4*>(u2);
        }
    } else if (bid < 264) {  // ---- oph GEMM ----
        const int m0 = (bid - 256) * 64;
        float acc[4][8] = {};
        const int r0 = (tid & 15) * 4;
        const int h0 = (tid >> 4) * 8;
        for (int k0 = 0; k0 < 128; k0 += 32) {
            __syncthreads();
            {
                const int r = tid >> 2, kk = (tid & 3) * 8;
                const float* src = ope + (size_t)(m0 + r) * 128 + (k0 + kk);
                float4 v0 = reinterpret_cast<const float4*>(src)[0];
                float4 v1 = reinterpret_cast<const float4*>(src)[1];
                lA[kk + 0][r] = v0.x; lA[kk + 1][r] = v0.y;
                lA[kk + 2][r] = v0.z; lA[kk + 3][r] = v0.w;
                lA[kk + 4][r] = v1.x; lA[kk + 5][r] = v1.y;
                lA[kk + 6][r] = v1.z; lA[kk + 7][r] = v1.w;
            }
            {
                const int kk = tid >> 3, hh = (tid & 7) * 16;
                const float* src = owW + (size_t)(k0 + kk) * 128 + hh;
#pragma unroll
                for (int q = 0; q < 4; ++q) {
                    float4 v = reinterpret_cast<const float4*>(src)[q];
                    lW1[kk][hh + 4 * q + 0] = v.x; lW1[kk][hh + 4 * q + 1] = v.y;
                    lW1[kk][hh + 4 * q + 2] = v.z; lW1[kk][hh + 4 * q + 3] = v.w;
                }
            }
            __syncthreads();
#pragma unroll
            for (int k = 0; k < 32; ++k) {
                float4 a  = *reinterpret_cast<const float4*>(&lA[k][r0]);
                float4 w0 = *reinterpret_cast<const float4*>(&lW1[k][h0]);
                float4 w1 = *reinterpret_cast<const float4*>(&lW1[k][h0 + 4]);
                float av[4] = {a.x, a.y, a.z, a.w};
                float wv[8] = {w0.x, w0.y, w0.z, w0.w, w1.x, w1.y, w1.z, w1.w};
#pragma unroll
                for (int i = 0; i < 4; ++i)
#pragma unroll
                    for (int j = 0; j < 8; ++j) acc[i][j] = fmaf(av[i], wv[j], acc[i][j]);
            }
        }
#pragma unroll
        for (int i = 0; i < 4; ++i) {
            alignas(16) unsigned short us[8];
#pragma unroll
            for (int j = 0; j < 8; ++j) us[j] = f2bf(acc[i][j] + owb[h0 + j]);
            *reinterpret_cast<uint4*>(oph + (size_t)(m0 + r0 + i) * 128 + h0) =
                *reinterpret_cast<const uint4*>(us);
        }
    } else if (bid < 272) {  // ---- compact (cap 512) ----
        const int b = bid - 264;
        if (tid == 0) cnt = 0;
        __syncthreads();
#pragma unroll
        for (int j = 0; j < 8; ++j) {
            const int w = tid * 8 + j;
            if (goal[b * Wn + w] != 0.f && wes[b * Wn + w] != 0.f) {
                const int p = atomicAdd(&cnt, 1);
                if (p < 512) widx[b * 512 + p] = w;
            }
        }
        __syncthreads();
        if (tid == 0) wcnt[b] = cnt < 512 ? cnt : 512;
    } else if (bid == 272) {  // ---- zero gwacc ----
        for (int idx = tid; idx < 1024; idx += 256) gwacc[idx] = 0.f;
    } else {  // ---- upW -> bf16 (2 blocks, 24576 elems each) ----
        const int base = (bid - 273) * 24576;
        for (int e = base + tid * 4; e < base + 24576; e += 1024) {
            float4 v = *reinterpret_cast<const float4*>(upW + e);
            alignas(8) unsigned short u[4] = {f2bf(v.x), f2bf(v.y), f2bf(v.z), f2bf(v.w)};
            *reinterpret_cast<uint2*>(upWbf + e) = *reinterpret_cast<const uint2*>(u);
        }
    }
}

// ---------------------------------------------------------------------------
// mega_agg6: TWO pooled slots per block (grid 2048 = 8 b x 256 pairs).
// All phases fused pairwise so both slots' independent loads are in flight
// together; upWbf loaded once for both slots; 4 waves busy in oph/p4.
// Odd wcnt handled via dummy slot (w1=w0, atomic skipped).
// ---------------------------------------------------------------------------
__global__ __launch_bounds__(256) void mega_agg6(const int* __restrict__ widx,
                                                 const int* __restrict__ wcnt,
                                                 const float* __restrict__ ww,
                                                 const float* __restrict__ wem,
                                                 const float* __restrict__ dep,
                                                 const float* __restrict__ wop,
                                                 const unsigned short* __restrict__ oph,
                                                 const unsigned short* __restrict__ wkh,
                                                 const unsigned short* __restrict__ wsh,
                                                 const unsigned short* __restrict__ upWbf,
                                                 const float* __restrict__ upb,
                                                 float* __restrict__ gwacc) {
    const int bid = blockIdx.x;           // b*256 + pair
    const int b = bid >> 8, pr = bid & 255;
    const int wc = wcnt[b];
    const int i0 = pr * 2;
    if (i0 >= wc) return;                 // uniform exit
    const bool has1 = (i0 + 1) < wc;
    const int w0 = widx[b * 512 + i0];
    const int w1 = has1 ? widx[b * 512 + i0 + 1] : w0;  // dummy if odd tail
    const int t = threadIdx.x;
    const int lane = t & 63, wv = t >> 6;

    __shared__ int kidx[2][512];
    __shared__ int sidx[2][256];
    __shared__ int kn[2], sn[2];
    __shared__ float part1[2][4][128];
    __shared__ float part2[2][4][128];
    __shared__ float nbL[2][384];
    __shared__ float gp16[16][128];
    if (t == 0) { kn[0] = 0; kn[1] = 0; sn[0] = 0; sn[1] = 0; }
    __syncthreads();

    // --- p1: fused ww&wem streams + dep scans for BOTH slots ---
    const float* wwr0 = ww  + ((size_t)(b * Wn + w0)) * Wn;
    const float* wmr0 = wem + ((size_t)(b * Wn + w0)) * Wn;
    const float* wwr1 = ww  + ((size_t)(b * Wn + w1)) * Wn;
    const float* wmr1 = wem + ((size_t)(b * Wn + w1)) * Wn;
#pragma unroll
    for (int q = 0; q < 2; ++q) {
        const int e0 = q * 1024 + t * 4;
        float4 v0 = *reinterpret_cast<const float4*>(wwr0 + e0);
        float4 m0 = *reinterpret_cast<const float4*>(wmr0 + e0);
        float4 v1 = *reinterpret_cast<const float4*>(wwr1 + e0);
        float4 m1 = *reinterpret_cast<const float4*>(wmr1 + e0);
        float vv0[4] = {v0.x, v0.y, v0.z, v0.w};
        float mm0[4] = {m0.x, m0.y, m0.z, m0.w};
        float vv1[4] = {v1.x, v1.y, v1.z, v1.w};
        float mm1[4] = {m1.x, m1.y, m1.z, m1.w};
#pragma unroll
        for (int j = 0; j < 4; ++j) {
            if (vv0[j] != 0.f && mm0[j] != 0.f) {
                int p = atomicAdd(&kn[0], 1);
                if (p < 512) kidx[0][p] = e0 + j;
            }
            if (vv1[j] != 0.f && mm1[j] != 0.f) {
                int p = atomicAdd(&kn[1], 1);
                if (p < 512) kidx[1][p] = e0 + j;
            }
        }
    }
    const int sD0 = w0 >> 9, lD0 = w0 & 511;
    const int sD1 = w1 >> 9, lD1 = w1 & 511;
    if (t < 128) {
        const float* dr0 = dep + ((size_t)((sD0 * Bn + b) * Ln + lD0)) * Ln + t * 4;
        const float* dr1 = dep + ((size_t)((sD1 * Bn + b) * Ln + lD1)) * Ln + t * 4;
        float4 v0 = *reinterpret_cast<const float4*>(dr0);
        float4 v1 = *reinterpret_cast<const float4*>(dr1);
        float vv0[4] = {v0.x, v0.y, v0.z, v0.w};
        float vv1[4] = {v1.x, v1.y, v1.z, v1.w};
#pragma unroll
        for (int j = 0; j < 4; ++j) {
            if (vv0[j] != 0.f) {
                int p = atomicAdd(&sn[0], 1);
                if (p < 256) sidx[0][p] = t * 4 + j;
            }
            if (vv1[j] != 0.f) {
                int p = atomicAdd(&sn[1], 1);
                if (p < 256) sidx[1][p] = t * 4 + j;
            }
        }
    }
    float m_op = 0.f;
    if (wv == 3)      m_op = wop[((size_t)(b * Wn + w0)) * NOPn + lane];
    else if (wv == 2) m_op = wop[((size_t)(b * Wn + w1)) * NOPn + lane];
    __syncthreads();

    const int nk0 = kn[0] < 512 ? kn[0] : 512;
    const int nk1 = kn[1] < 512 ? kn[1] : 512;
    const int ns0 = sn[0] < 256 ? sn[0] : 256;
    const int ns1 = sn[1] < 256 ? sn[1] : 256;
    const int hl = lane >> 5, c = lane & 31;

    // --- p3: fused gathers (both slots' loads in flight per iteration) ---
    {   // slot1 (wkh)
        float aA[4] = {}, aB[4] = {};
        const int pm = nk0 > nk1 ? nk0 : nk1;
        for (int p = wv * 2 + hl; p < pm; p += 8) {
            if (p < nk0) {
                const int w = kidx[0][p];
                const int s = w >> 9, l = w & 511;
                ushort4 x = *reinterpret_cast<const ushort4*>(
                    wkh + ((size_t)((s * Bn + b) * Ln + l)) * Hn + c * 4);
                aA[0] += bf2f(x.x); aA[1] += bf2f(x.y);
                aA[2] += bf2f(x.z); aA[3] += bf2f(x.w);
            }
            if (p < nk1) {
                const int w = kidx[1][p];
                const int s = w >> 9, l = w & 511;
                ushort4 x = *reinterpret_cast<const ushort4*>(
                    wkh + ((size_t)((s * Bn + b) * Ln + l)) * Hn + c * 4);
                aB[0] += bf2f(x.x); aB[1] += bf2f(x.y);
                aB[2] += bf2f(x.z); aB[3] += bf2f(x.w);
            }
        }
#pragma unroll
        for (int q = 0; q < 4; ++q) {
            aA[q] += __shfl_xor(aA[q], 32);
            aB[q] += __shfl_xor(aB[q], 32);
        }
        if (hl == 0) {
#pragma unroll
            for (int q = 0; q < 4; ++q) {
                part1[0][wv][c * 4 + q] = aA[q];
                part1[1][wv][c * 4 + q] = aB[q];
            }
        }
    }
    {   // slot2 (wsh)
        const unsigned short* base0 = wsh + (size_t)((sD0 * Bn + b) * Ln) * Hn + c * 4;
        const unsigned short* base1 = wsh + (size_t)((sD1 * Bn + b) * Ln) * Hn + c * 4;
        float aA[4] = {}, aB[4] = {};
        const int pm = ns0 > ns1 ? ns0 : ns1;
        for (int p = wv * 2 + hl; p < pm; p += 8) {
            if (p < ns0) {
                ushort4 x = *reinterpret_cast<const ushort4*>(base0 + (size_t)sidx[0][p] * Hn);
                aA[0] += bf2f(x.x); aA[1] += bf2f(x.y);
                aA[2] += bf2f(x.z); aA[3] += bf2f(x.w);
            }
            if (p < ns1) {
                ushort4 x = *reinterpret_cast<const ushort4*>(base1 + (size_t)sidx[1][p] * Hn);
                aB[0] += bf2f(x.x); aB[1] += bf2f(x.y);
                aB[2] += bf2f(x.z); aB[3] += bf2f(x.w);
            }
        }
#pragma unroll
        for (int q = 0; q < 4; ++q) {
            aA[q] += __shfl_xor(aA[q], 32);
            aB[q] += __shfl_xor(aB[q], 32);
        }
        if (hl == 0) {
#pragma unroll
            for (int q = 0; q < 4; ++q) {
                part2[0][wv][c * 4 + q] = aA[q];
                part2[1][wv][c * 4 + q] = aB[q];
            }
        }
    }
    if (wv >= 2) {  // slot0 (oph): wv3->u0, wv2->u1
        const int u = 3 - wv;
        unsigned long long bal = __ballot(m_op != 0.f);
        float a0 = 0.f, a1 = 0.f;
        const unsigned short* base = oph + (size_t)b * NOPn * Hn + 2 * lane;
        while (bal) {
            const int o = __ffsll(bal) - 1;
            bal &= bal - 1;
            ushort2 v = *reinterpret_cast<const ushort2*>(base + o * Hn);
            a0 += bf2f(v.x);
            a1 += bf2f(v.y);
        }
        float ss = a0 * a0 + a1 * a1;
#pragma unroll
        for (int off = 1; off < 64; off <<= 1) ss += __shfl_xor(ss, off);
        const float sc = 1.f / (sqrtf(ss) + 1e-30f);
        nbL[u][2 * lane]     = a0 * sc;
        nbL[u][2 * lane + 1] = a1 * sc;
    }
    __syncthreads();

    // --- p4: reduce+normalize; wv0/wv1 slot1(u=0/1), wv2/wv3 slot2(u=0/1) ---
    {
        const int u = wv & 1;
        if (wv < 2) {
            float s0 = 0.f, s1 = 0.f;
#pragma unroll
            for (int q = 0; q < 4; ++q) {
                s0 += part1[u][q][2 * lane];
                s1 += part1[u][q][2 * lane + 1];
            }
            float ss = s0 * s0 + s1 * s1;
#pragma unroll
            for (int off = 1; off < 64; off <<= 1) ss += __shfl_xor(ss, off);
            const float sc = 1.f / (sqrtf(ss) + 1e-30f);
            nbL[u][128 + 2 * lane]     = s0 * sc;
            nbL[u][128 + 2 * lane + 1] = s1 * sc;
        } else {
            float s0 = 0.f, s1 = 0.f;
#pragma unroll
            for (int q = 0; q < 4; ++q) {
                s0 += part2[u][q][2 * lane];
                s1 += part2[u][q][2 * lane + 1];
            }
            float ss = s0 * s0 + s1 * s1;
#pragma unroll
            for (int off = 1; off < 64; off <<= 1) ss += __shfl_xor(ss, off);
            const float sc = 1.f / (sqrtf(ss) + 1e-30f);
            nbL[u][256 + 2 * lane]     = s0 * sc;
            nbL[u][256 + 2 * lane + 1] = s1 * sc;
        }
    }
    __syncthreads();

    // --- p5: shared-weight up-GEMV for both slots. thread (i8=t&15)*8,
    // j=t>>4: 24 uint4 loads, each feeding 8 FMAs per slot. ---
    const int i8 = (t & 15) * 8, j = t >> 4;
    float aA[8] = {}, aB[8] = {};
#pragma unroll
    for (int r = 0; r < 24; ++r) {
        const int k = r * 16 + j;
        const uint4 w = *reinterpret_cast<const uint4*>(upWbf + (size_t)k * 128 + i8);
        const float x0 = nbL[0][k], x1 = nbL[1][k];
        float wl;
        wl = bflo(w.x); aA[0] = fmaf(x0, wl, aA[0]); aB[0] = fmaf(x1, wl, aB[0]);
        wl = bfhi(w.x); aA[1] = fmaf(x0, wl, aA[1]); aB[1] = fmaf(x1, wl, aB[1]);
        wl = bflo(w.y); aA[2] = fmaf(x0, wl, aA[2]); aB[2] = fmaf(x1, wl, aB[2]);
        wl = bfhi(w.y); aA[3] = fmaf(x0, wl, aA[3]); aB[3] = fmaf(x1, wl, aB[3]);
        wl = bflo(w.z); aA[4] = fmaf(x0, wl, aA[4]); aB[4] = fmaf(x1, wl, aB[4]);
        wl = bfhi(w.z); aA[5] = fmaf(x0, wl, aA[5]); aB[5] = fmaf(x1, wl, aB[5]);
        wl = bflo(w.w); aA[6] = fmaf(x0, wl, aA[6]); aB[6] = fmaf(x1, wl, aB[6]);
        wl = bfhi(w.w); aA[7] = fmaf(x0, wl, aA[7]); aB[7] = fmaf(x1, wl, aB[7]);
    }
#pragma unroll
    for (int q = 0; q < 8; ++q) gp16[j][i8 + q] = aA[q];
    __syncthreads();
    if (t < 128) {
        float g = upb[t];
#pragma unroll
        for (int jj = 0; jj < 16; ++jj) g += gp16[jj][t];
        g = fmaxf(g, 0.f);
        atomicAdd(&gwacc[b * 128 + t], g);
    }
    if (has1) {
        __syncthreads();
#pragma unroll
        for (int q = 0; q < 8; ++q) gp16[j][i8 + q] = aB[q];
        __syncthreads();
        if (t < 128) {
            float g = upb[t];
#pragma unroll
            for (int jj = 0; jj < 16; ++jj) g += gp16[jj][t];
            g = fmaxf(g, 0.f);
            atomicAdd(&gwacc[b * 128 + t], g);
        }
    }
}

// ---------------------------------------------------------------------------
// final4: read pooled sums, mean, two GEMVs, gates. 8 blocks x 128 thr.
// ---------------------------------------------------------------------------
__global__ __launch_bounds__(128) void final4_k(const int* __restrict__ wcnt,
                                                const float* __restrict__ gwacc,
                                                const float* __restrict__ nh,
                                                const float* __restrict__ wgW,
                                                const float* __restrict__ wgb,
                                                const float* __restrict__ fgW,
                                                const float* __restrict__ fgb,
                                                float* __restrict__ out) {
    const int b = blockIdx.x, t = threadIdx.x;
    __shared__ float gw[Dn], nhs[Dn];
    const float inv = 1.f / ((float)wcnt[b] + 1e-30f);
    gw[t]  = gwacc[b * Dn + t] * inv;
    nhs[t] = nh[b * Dn + t];
    __syncthreads();
    float gu = wgb[t];
    for (int d = 0; d < Dn; ++d) gu = fmaf(gw[d], wgW[d * Dn + t], gu);
    gu = fmaxf(gu, 0.f);
    float fg = fgb[t];
    for (int d = 0; d < Dn; ++d) fg = fmaf(gw[d], fgW[d * Dn + t], fg);
    for (int d = 0; d < Dn; ++d) fg = fmaf(nhs[d], fgW[(Dn + d) * Dn + t], fg);
    const float forget = 1.f / (1.f + expf(-fg));
    out[b * Dn + t] = fmaxf(forget, 0.1f) * nhs[t] + (1.f - forget) * gu;
}

// ---------------------------------------------------------------------------
extern "C" void kernel_launch(void* const* d_in, const int* in_sizes, int n_in,
                              void* d_out, int out_size, void* d_ws, size_t ws_size,
                              hipStream_t stream) {
    (void)in_sizes; (void)n_in; (void)out_size; (void)ws_size;
    const float* word_outputs        = (const float*)d_in[0];
    const float* node_hidden         = (const float*)d_in[1];
    const float* op_embedding        = (const float*)d_in[2];
    const float* word_operator       = (const float*)d_in[3];
    const float* word_word           = (const float*)d_in[4];
    const float* depend_relation     = (const float*)d_in[5];
    const float* word_exist_matrix   = (const float*)d_in[6];
    const float* word_exist_sequence = (const float*)d_in[7];
    const float* goal_word           = (const float*)d_in[8];
    const float* o_w_W = (const float*)d_in[9];
    const float* o_w_b = (const float*)d_in[10];
    const float* wk_W  = (const float*)d_in[11];
    const float* wk_b  = (const float*)d_in[12];
    const float* ws_W  = (const float*)d_in[13];
    const float* ws_b  = (const float*)d_in[14];
    const float* up_W  = (const float*)d_in[15];
    const float* up_b  = (const float*)d_in[16];
    const float* wg_W  = (const float*)d_in[17];
    const float* wg_b  = (const float*)d_in[18];
    const float* fg_W  = (const float*)d_in[19];
    const float* fg_b  = (const float*)d_in[20];
    float* out = (float*)d_out;

    char* ws = (char*)d_ws;
    unsigned short* oph   = (unsigned short*)(ws + 0);                      // 128 KB
    unsigned short* wkh   = (unsigned short*)(ws + (1u << 20));             // 4 MB
    unsigned short* wsh   = (unsigned short*)(ws + (5u << 20));             // 4 MB
    int* widx             = (int*)(ws + (9u << 20));                        // 16 KB
    int* wcnt             = (int*)(ws + (9u << 20) + 32768);                // 32 B
    float* gwacc          = (float*)(ws + (9u << 20) + 65536);              // 4 KB
    unsigned short* upWbf = (unsigned short*)(ws + (9u << 20) + 131072);    // 96 KB

    prep_k<<<275, 256, 0, stream>>>(word_outputs, wk_W, ws_W, wk_b, ws_b, wkh, wsh,
                                    op_embedding, o_w_W, o_w_b, oph,
                                    goal_word, word_exist_sequence, widx, wcnt, gwacc,
                                    up_W, upWbf);
    mega_agg6<<<2048, 256, 0, stream>>>(widx, wcnt, word_word, word_exist_matrix,
                                        depend_relation, word_operator, oph, wkh, wsh,
                                        upWbf, up_b, gwacc);
    final4_k<<<8, 128, 0, stream>>>(wcnt, gwacc, node_hidden,
                                    wg_W, wg_b, fg_W, fg_b, out);
}

// Round 9
// 339.158 us; speedup vs baseline: 1.0664x; 1.0664x over previous
//
#include <hip/hip_runtime.h>
#include <math.h>

#define Sn 4
#define Bn 8
#define Ln 512
#define Dn 128
#define Hn 128
#define NOPn 64
#define Wn 2048

// ESTABLISHED: inputs fp32 insertion order; output fp32; bf16-space compare
// (thr 3.6e-2); ws = 512MB; harness tax ~220-260us/iter (restore+poison+gaps,
// ~10us per dispatch; 512MB poison fill alone is 78us @86% HBM peak).
// R20 362 (4k). R21 354 (3k). R22-R26: in-kernel completion schemes all lose.
// R27 350.6: bf16 upWbf + fused ww&wem + k-split. R28 345.0 (best): wide
// loads (uint4 GEMV, ushort4 gathers). R29 FAILED 361.7: 2 slots/block ->
// 25KB LDS + extra barriers lost more TLP than paired ILP gained.
// R30 (this = R28 + XCD swizzle): b = bid&7, i = bid>>3. Round-robin
// workgroup->XCD dispatch then pins all slots of batch b to XCD b; per-b L2
// footprint (wkh/wsh slices 1MB + upWbf 96KB) fits one XCD's 4MB L2, where
// the old slot=b*512+i interleaving forced every XCD to cache all 8MB.

__device__ __forceinline__ float bf2f(unsigned short u) {
    return __uint_as_float(((unsigned int)u) << 16);
}
__device__ __forceinline__ float bflo(unsigned int u) {
    return __uint_as_float(u << 16);
}
__device__ __forceinline__ float bfhi(unsigned int u) {
    return __uint_as_float(u & 0xFFFF0000u);
}
__device__ __forceinline__ unsigned short f2bf(float f) {
    unsigned int u = __float_as_uint(f);
    return (unsigned short)((u + 0x7FFFu + ((u >> 16) & 1u)) >> 16);  // RNE
}

// ---------------------------------------------------------------------------
// prep_k: blockIdx branches.
//   0..255   : dual GEMM tile (wkh/wsh from word_outputs)
//   256..263 : op-embedding GEMM tile (oph)
//   264..271 : compact pooled indices for b = bid-264 (cap 512)
//   272      : zero gwacc
//   273..274 : convert upW (384x128 fp32) -> upWbf (bf16)
// ---------------------------------------------------------------------------
__global__ __launch_bounds__(256) void prep_k(const float* __restrict__ A,
                                              const float* __restrict__ W1,
                                              const float* __restrict__ W2,
                                              const float* __restrict__ b1,
                                              const float* __restrict__ b2,
                                              unsigned short* __restrict__ C1,
                                              unsigned short* __restrict__ C2,
                                              const float* __restrict__ ope,
                                              const float* __restrict__ owW,
                                              const float* __restrict__ owb,
                                              unsigned short* __restrict__ oph,
                                              const float* __restrict__ goal,
                                              const float* __restrict__ wes,
                                              int* __restrict__ widx,
                                              int* __restrict__ wcnt,
                                              float* __restrict__ gwacc,
                                              const float* __restrict__ upW,
                                              unsigned short* __restrict__ upWbf) {
    __shared__ __align__(16) float lA[32][68];
    __shared__ __align__(16) float lW1[32][132];
    __shared__ __align__(16) float lW2[32][132];
    __shared__ int cnt;
    const int bid = blockIdx.x, tid = threadIdx.x;

    if (bid < 256) {  // ---- dual GEMM ----
        const int m0 = bid * 64;
        float acc1[4][8] = {}, acc2[4][8] = {};
        const int r0 = (tid & 15) * 4;
        const int h0 = (tid >> 4) * 8;
        for (int k0 = 0; k0 < 128; k0 += 32) {
            __syncthreads();
            {
                const int r = tid >> 2, kk = (tid & 3) * 8;
                const float* src = A + (size_t)(m0 + r) * 128 + (k0 + kk);
                float4 v0 = reinterpret_cast<const float4*>(src)[0];
                float4 v1 = reinterpret_cast<const float4*>(src)[1];
                lA[kk + 0][r] = v0.x; lA[kk + 1][r] = v0.y;
                lA[kk + 2][r] = v0.z; lA[kk + 3][r] = v0.w;
                lA[kk + 4][r] = v1.x; lA[kk + 5][r] = v1.y;
                lA[kk + 6][r] = v1.z; lA[kk + 7][r] = v1.w;
            }
            {
                const int kk = tid >> 3, hh = (tid & 7) * 16;
                const float* s1 = W1 + (size_t)(k0 + kk) * 128 + hh;
                const float* s2 = W2 + (size_t)(k0 + kk) * 128 + hh;
#pragma unroll
                for (int q = 0; q < 4; ++q) {
                    float4 v1 = reinterpret_cast<const float4*>(s1)[q];
                    float4 v2 = reinterpret_cast<const float4*>(s2)[q];
                    lW1[kk][hh + 4 * q + 0] = v1.x; lW1[kk][hh + 4 * q + 1] = v1.y;
                    lW1[kk][hh + 4 * q + 2] = v1.z; lW1[kk][hh + 4 * q + 3] = v1.w;
                    lW2[kk][hh + 4 * q + 0] = v2.x; lW2[kk][hh + 4 * q + 1] = v2.y;
                    lW2[kk][hh + 4 * q + 2] = v2.z; lW2[kk][hh + 4 * q + 3] = v2.w;
                }
            }
            __syncthreads();
#pragma unroll
            for (int k = 0; k < 32; ++k) {
                float4 a   = *reinterpret_cast<const float4*>(&lA[k][r0]);
                float4 w10 = *reinterpret_cast<const float4*>(&lW1[k][h0]);
                float4 w11 = *reinterpret_cast<const float4*>(&lW1[k][h0 + 4]);
                float4 w20 = *reinterpret_cast<const float4*>(&lW2[k][h0]);
                float4 w21 = *reinterpret_cast<const float4*>(&lW2[k][h0 + 4]);
                float av[4] = {a.x, a.y, a.z, a.w};
                float wv1[8] = {w10.x, w10.y, w10.z, w10.w, w11.x, w11.y, w11.z, w11.w};
                float wv2[8] = {w20.x, w20.y, w20.z, w20.w, w21.x, w21.y, w21.z, w21.w};
#pragma unroll
                for (int i = 0; i < 4; ++i)
#pragma unroll
                    for (int j = 0; j < 8; ++j) {
                        acc1[i][j] = fmaf(av[i], wv1[j], acc1[i][j]);
                        acc2[i][j] = fmaf(av[i], wv2[j], acc2[i][j]);
                    }
            }
        }
#pragma unroll
        for (int i = 0; i < 4; ++i) {
            alignas(16) unsigned short u1[8], u2[8];
#pragma unroll
            for (int j = 0; j < 8; ++j) {
                u1[j] = f2bf(acc1[i][j] + b1[h0 + j]);
                u2[j] = f2bf(acc2[i][j] + b2[h0 + j]);
            }
            const size_t off = (size_t)(m0 + r0 + i) * 128 + h0;
            *reinterpret_cast<uint4*>(C1 + off) = *reinterpret_cast<const uint4*>(u1);
            *reinterpret_cast<uint4*>(C2 + off) = *reinterpret_cast<const uint4*>(u2);
        }
    } else if (bid < 264) {  // ---- oph GEMM ----
        const int m0 = (bid - 256) * 64;
        float acc[4][8] = {};
        const int r0 = (tid & 15) * 4;
        const int h0 = (tid >> 4) * 8;
        for (int k0 = 0; k0 < 128; k0 += 32) {
            __syncthreads();
            {
                const int r = tid >> 2, kk = (tid & 3) * 8;
                const float* src = ope + (size_t)(m0 + r) * 128 + (k0 + kk);
                float4 v0 = reinterpret_cast<const float4*>(src)[0];
                float4 v1 = reinterpret_cast<const float4*>(src)[1];
                lA[kk + 0][r] = v0.x; lA[kk + 1][r] = v0.y;
                lA[kk + 2][r] = v0.z; lA[kk + 3][r] = v0.w;
                lA[kk + 4][r] = v1.x; lA[kk + 5][r] = v1.y;
                lA[kk + 6][r] = v1.z; lA[kk + 7][r] = v1.w;
            }
            {
                const int kk = tid >> 3, hh = (tid & 7) * 16;
                const float* src = owW + (size_t)(k0 + kk) * 128 + hh;
#pragma unroll
                for (int q = 0; q < 4; ++q) {
                    float4 v = reinterpret_cast<const float4*>(src)[q];
                    lW1[kk][hh + 4 * q + 0] = v.x; lW1[kk][hh + 4 * q + 1] = v.y;
                    lW1[kk][hh + 4 * q + 2] = v.z; lW1[kk][hh + 4 * q + 3] = v.w;
                }
            }
            __syncthreads();
#pragma unroll
            for (int k = 0; k < 32; ++k) {
                float4 a  = *reinterpret_cast<const float4*>(&lA[k][r0]);
                float4 w0 = *reinterpret_cast<const float4*>(&lW1[k][h0]);
                float4 w1 = *reinterpret_cast<const float4*>(&lW1[k][h0 + 4]);
                float av[4] = {a.x, a.y, a.z, a.w};
                float wv[8] = {w0.x, w0.y, w0.z, w0.w, w1.x, w1.y, w1.z, w1.w};
#pragma unroll
                for (int i = 0; i < 4; ++i)
#pragma unroll
                    for (int j = 0; j < 8; ++j) acc[i][j] = fmaf(av[i], wv[j], acc[i][j]);
            }
        }
#pragma unroll
        for (int i = 0; i < 4; ++i) {
            alignas(16) unsigned short us[8];
#pragma unroll
            for (int j = 0; j < 8; ++j) us[j] = f2bf(acc[i][j] + owb[h0 + j]);
            *reinterpret_cast<uint4*>(oph + (size_t)(m0 + r0 + i) * 128 + h0) =
                *reinterpret_cast<const uint4*>(us);
        }
    } else if (bid < 272) {  // ---- compact (cap 512) ----
        const int b = bid - 264;
        if (tid == 0) cnt = 0;
        __syncthreads();
#pragma unroll
        for (int j = 0; j < 8; ++j) {
            const int w = tid * 8 + j;
            if (goal[b * Wn + w] != 0.f && wes[b * Wn + w] != 0.f) {
                const int p = atomicAdd(&cnt, 1);
                if (p < 512) widx[b * 512 + p] = w;
            }
        }
        __syncthreads();
        if (tid == 0) wcnt[b] = cnt < 512 ? cnt : 512;
    } else if (bid == 272) {  // ---- zero gwacc ----
        for (int idx = tid; idx < 1024; idx += 256) gwacc[idx] = 0.f;
    } else {  // ---- upW -> bf16 (2 blocks, 24576 elems each) ----
        const int base = (bid - 273) * 24576;
        for (int e = base + tid * 4; e < base + 24576; e += 1024) {
            float4 v = *reinterpret_cast<const float4*>(upW + e);
            alignas(8) unsigned short u[4] = {f2bf(v.x), f2bf(v.y), f2bf(v.z), f2bf(v.w)};
            *reinterpret_cast<uint2*>(upWbf + e) = *reinterpret_cast<const uint2*>(u);
        }
    }
}

// ---------------------------------------------------------------------------
// mega_agg7: one block per pooled slot, XCD-swizzled: b = bid&7, i = bid>>3.
// Under round-robin workgroup->XCD dispatch, all slots of batch b land on
// XCD b -> per-XCD L2 working set ~1.1MB (fits 4MB) instead of 8MB.
// Otherwise identical to R28's mega_agg5 (wide loads, [16][128] GEMV tile).
// ---------------------------------------------------------------------------
__global__ __launch_bounds__(256) void mega_agg7(const int* __restrict__ widx,
                                                 const int* __restrict__ wcnt,
                                                 const float* __restrict__ ww,
                                                 const float* __restrict__ wem,
                                                 const float* __restrict__ dep,
                                                 const float* __restrict__ wop,
                                                 const unsigned short* __restrict__ oph,
                                                 const unsigned short* __restrict__ wkh,
                                                 const unsigned short* __restrict__ wsh,
                                                 const unsigned short* __restrict__ upWbf,
                                                 const float* __restrict__ upb,
                                                 float* __restrict__ gwacc) {
    const int bid = blockIdx.x;
    const int b = bid & 7, i = bid >> 3;  // XCD swizzle: batch -> XCD
    if (i >= wcnt[b]) return;             // uniform exit
    const int w_dst = widx[b * 512 + i];
    const int t = threadIdx.x;
    const int lane = t & 63, wv = t >> 6;

    __shared__ int kidx[512];
    __shared__ int sidx[256];
    __shared__ int kn, sn;
    __shared__ float part1[4][128];
    __shared__ float part2[4][128];
    __shared__ float nbL[384];
    __shared__ float gp16[16][128];
    if (t == 0) { kn = 0; sn = 0; }
    __syncthreads();

    // --- p1: fused ww & wem row streams + dep row scan ---
    const float* wwr = ww  + ((size_t)(b * Wn + w_dst)) * Wn;
    const float* wmr = wem + ((size_t)(b * Wn + w_dst)) * Wn;
#pragma unroll
    for (int q = 0; q < 2; ++q) {
        const int e0 = q * 1024 + t * 4;
        float4 v = *reinterpret_cast<const float4*>(wwr + e0);
        float4 m = *reinterpret_cast<const float4*>(wmr + e0);
        float vv[4] = {v.x, v.y, v.z, v.w};
        float mm[4] = {m.x, m.y, m.z, m.w};
#pragma unroll
        for (int j = 0; j < 4; ++j)
            if (vv[j] != 0.f && mm[j] != 0.f) {
                int p = atomicAdd(&kn, 1);
                if (p < 512) kidx[p] = e0 + j;
            }
    }
    const int sD = w_dst >> 9, lD = w_dst & 511;
    if (t < 128) {
        const float* dr = dep + ((size_t)((sD * Bn + b) * Ln + lD)) * Ln + t * 4;
        float4 v = *reinterpret_cast<const float4*>(dr);
        float vv[4] = {v.x, v.y, v.z, v.w};
#pragma unroll
        for (int j = 0; j < 4; ++j)
            if (vv[j] != 0.f) {
                int p = atomicAdd(&sn, 1);
                if (p < 256) sidx[p] = t * 4 + j;
            }
    }
    float m_op = 0.f;
    if (wv == 3) m_op = wop[((size_t)(b * Wn + w_dst)) * NOPn + lane];
    __syncthreads();

    const int nk = kn < 512 ? kn : 512;
    const int ns = sn < 256 ? sn : 256;

    // --- p3: gathers (ushort4/lane, 2 rows per wave per iteration) ---
    {   // slot1
        const int hl = lane >> 5, c = lane & 31;
        float a0 = 0.f, a1 = 0.f, a2 = 0.f, a3 = 0.f;
        for (int p = wv * 2 + hl; p < nk; p += 8) {
            const int w = kidx[p];
            const int s = w >> 9, l = w & 511;
            ushort4 x = *reinterpret_cast<const ushort4*>(
                wkh + ((size_t)((s * Bn + b) * Ln + l)) * Hn + c * 4);
            a0 += bf2f(x.x); a1 += bf2f(x.y); a2 += bf2f(x.z); a3 += bf2f(x.w);
        }
        a0 += __shfl_xor(a0, 32); a1 += __shfl_xor(a1, 32);
        a2 += __shfl_xor(a2, 32); a3 += __shfl_xor(a3, 32);
        if (hl == 0) {
            part1[wv][c * 4 + 0] = a0; part1[wv][c * 4 + 1] = a1;
            part1[wv][c * 4 + 2] = a2; part1[wv][c * 4 + 3] = a3;
        }
    }
    {   // slot2
        const int hl = lane >> 5, c = lane & 31;
        const unsigned short* base = wsh + (size_t)((sD * Bn + b) * Ln) * Hn + c * 4;
        float a0 = 0.f, a1 = 0.f, a2 = 0.f, a3 = 0.f;
        for (int p = wv * 2 + hl; p < ns; p += 8) {
            ushort4 x = *reinterpret_cast<const ushort4*>(base + (size_t)sidx[p] * Hn);
            a0 += bf2f(x.x); a1 += bf2f(x.y); a2 += bf2f(x.z); a3 += bf2f(x.w);
        }
        a0 += __shfl_xor(a0, 32); a1 += __shfl_xor(a1, 32);
        a2 += __shfl_xor(a2, 32); a3 += __shfl_xor(a3, 32);
        if (hl == 0) {
            part2[wv][c * 4 + 0] = a0; part2[wv][c * 4 + 1] = a1;
            part2[wv][c * 4 + 2] = a2; part2[wv][c * 4 + 3] = a3;
        }
    }
    if (wv == 3) {  // slot0 -> nbL[0:128]
        unsigned long long bal = __ballot(m_op != 0.f);
        float a0 = 0.f, a1 = 0.f;
        const unsigned short* base = oph + (size_t)b * NOPn * Hn + 2 * lane;
        while (bal) {
            const int o = __ffsll(bal) - 1;
            bal &= bal - 1;
            ushort2 v = *reinterpret_cast<const ushort2*>(base + o * Hn);
            a0 += bf2f(v.x);
            a1 += bf2f(v.y);
        }
        float ss = a0 * a0 + a1 * a1;
#pragma unroll
        for (int off = 1; off < 64; off <<= 1) ss += __shfl_xor(ss, off);
        const float sc = 1.f / (sqrtf(ss) + 1e-30f);
        nbL[2 * lane]     = a0 * sc;
        nbL[2 * lane + 1] = a1 * sc;
    }
    __syncthreads();

    // --- p4: reduce+normalize slot1 (wave0) and slot2 (wave1) ---
    if (wv == 0) {
        float s0 = 0.f, s1 = 0.f;
#pragma unroll
        for (int q = 0; q < 4; ++q) {
            s0 += part1[q][2 * lane];
            s1 += part1[q][2 * lane + 1];
        }
        float ss = s0 * s0 + s1 * s1;
#pragma unroll
        for (int off = 1; off < 64; off <<= 1) ss += __shfl_xor(ss, off);
        const float sc = 1.f / (sqrtf(ss) + 1e-30f);
        nbL[128 + 2 * lane]     = s0 * sc;
        nbL[128 + 2 * lane + 1] = s1 * sc;
    } else if (wv == 1) {
        float s0 = 0.f, s1 = 0.f;
#pragma unroll
        for (int q = 0; q < 4; ++q) {
            s0 += part2[q][2 * lane];
            s1 += part2[q][2 * lane + 1];
        }
        float ss = s0 * s0 + s1 * s1;
#pragma unroll
        for (int off = 1; off < 64; off <<= 1) ss += __shfl_xor(ss, off);
        const float sc = 1.f / (sqrtf(ss) + 1e-30f);
        nbL[256 + 2 * lane]     = s0 * sc;
        nbL[256 + 2 * lane + 1] = s1 * sc;
    }
    __syncthreads();

    // --- p5: wide-load up-GEMV. thread (i=t&15, j=t>>4): 8 dims i*8..i*8+7,
    // k = r*16 + j over 24 rounds; uint4 load = 8 bf16 per round. ---
    {
        const int i8 = (t & 15) * 8, j = t >> 4;
        float a[8] = {};
#pragma unroll
        for (int r = 0; r < 24; ++r) {
            const int k = r * 16 + j;
            const uint4 w = *reinterpret_cast<const uint4*>(upWbf + (size_t)k * 128 + i8);
            const float x = nbL[k];
            a[0] = fmaf(x, bflo(w.x), a[0]); a[1] = fmaf(x, bfhi(w.x), a[1]);
            a[2] = fmaf(x, bflo(w.y), a[2]); a[3] = fmaf(x, bfhi(w.y), a[3]);
            a[4] = fmaf(x, bflo(w.z), a[4]); a[5] = fmaf(x, bfhi(w.z), a[5]);
            a[6] = fmaf(x, bflo(w.w), a[6]); a[7] = fmaf(x, bfhi(w.w), a[7]);
        }
#pragma unroll
        for (int q = 0; q < 8; ++q) gp16[j][i8 + q] = a[q];
    }
    __syncthreads();
    if (t < 128) {
        float g = upb[t];
#pragma unroll
        for (int j = 0; j < 16; ++j) g += gp16[j][t];
        g = fmaxf(g, 0.f);
        atomicAdd(&gwacc[b * 128 + t], g);
    }
}

// ---------------------------------------------------------------------------
// final4: read pooled sums, mean, two GEMVs, gates. 8 blocks x 128 thr.
// ---------------------------------------------------------------------------
__global__ __launch_bounds__(128) void final4_k(const int* __restrict__ wcnt,
                                                const float* __restrict__ gwacc,
                                                const float* __restrict__ nh,
                                                const float* __restrict__ wgW,
                                                const float* __restrict__ wgb,
                                                const float* __restrict__ fgW,
                                                const float* __restrict__ fgb,
                                                float* __restrict__ out) {
    const int b = blockIdx.x, t = threadIdx.x;
    __shared__ float gw[Dn], nhs[Dn];
    const float inv = 1.f / ((float)wcnt[b] + 1e-30f);
    gw[t]  = gwacc[b * Dn + t] * inv;
    nhs[t] = nh[b * Dn + t];
    __syncthreads();
    float gu = wgb[t];
    for (int d = 0; d < Dn; ++d) gu = fmaf(gw[d], wgW[d * Dn + t], gu);
    gu = fmaxf(gu, 0.f);
    float fg = fgb[t];
    for (int d = 0; d < Dn; ++d) fg = fmaf(gw[d], fgW[d * Dn + t], fg);
    for (int d = 0; d < Dn; ++d) fg = fmaf(nhs[d], fgW[(Dn + d) * Dn + t], fg);
    const float forget = 1.f / (1.f + expf(-fg));
    out[b * Dn + t] = fmaxf(forget, 0.1f) * nhs[t] + (1.f - forget) * gu;
}

// ---------------------------------------------------------------------------
extern "C" void kernel_launch(void* const* d_in, const int* in_sizes, int n_in,
                              void* d_out, int out_size, void* d_ws, size_t ws_size,
                              hipStream_t stream) {
    (void)in_sizes; (void)n_in; (void)out_size; (void)ws_size;
    const float* word_outputs        = (const float*)d_in[0];
    const float* node_hidden         = (const float*)d_in[1];
    const float* op_embedding        = (const float*)d_in[2];
    const float* word_operator       = (const float*)d_in[3];
    const float* word_word           = (const float*)d_in[4];
    const float* depend_relation     = (const float*)d_in[5];
    const float* word_exist_matrix   = (const float*)d_in[6];
    const float* word_exist_sequence = (const float*)d_in[7];
    const float* goal_word           = (const float*)d_in[8];
    const float* o_w_W = (const float*)d_in[9];
    const float* o_w_b = (const float*)d_in[10];
    const float* wk_W  = (const float*)d_in[11];
    const float* wk_b  = (const float*)d_in[12];
    const float* ws_W  = (const float*)d_in[13];
    const float* ws_b  = (const float*)d_in[14];
    const float* up_W  = (const float*)d_in[15];
    const float* up_b  = (const float*)d_in[16];
    const float* wg_W  = (const float*)d_in[17];
    const float* wg_b  = (const float*)d_in[18];
    const float* fg_W  = (const float*)d_in[19];
    const float* fg_b  = (const float*)d_in[20];
    float* out = (float*)d_out;

    char* ws = (char*)d_ws;
    unsigned short* oph   = (unsigned short*)(ws + 0);                      // 128 KB
    unsigned short* wkh   = (unsigned short*)(ws + (1u << 20));             // 4 MB
    unsigned short* wsh   = (unsigned short*)(ws + (5u << 20));             // 4 MB
    int* widx             = (int*)(ws + (9u << 20));                        // 16 KB
    int* wcnt             = (int*)(ws + (9u << 20) + 32768);                // 32 B
    float* gwacc          = (float*)(ws + (9u << 20) + 65536);              // 4 KB
    unsigned short* upWbf = (unsigned short*)(ws + (9u << 20) + 131072);    // 96 KB

    prep_k<<<275, 256, 0, stream>>>(word_outputs, wk_W, ws_W, wk_b, ws_b, wkh, wsh,
                                    op_embedding, o_w_W, o_w_b, oph,
                                    goal_word, word_exist_sequence, widx, wcnt, gwacc,
                                    up_W, upWbf);
    mega_agg7<<<4096, 256, 0, stream>>>(widx, wcnt, word_word, word_exist_matrix,
                                        depend_relation, word_operator, oph, wkh, wsh,
                                        upWbf, up_b, gwacc);
    final4_k<<<8, 128, 0, stream>>>(wcnt, gwacc, node_hidden,
                                    wg_W, wg_b, fg_W, fg_b, out);
}